// Round 4
// baseline (528.437 us; speedup 1.0000x reference)
//
#include <hip/hip_runtime.h>
#include <math.h>

#define CC 96
#define BB 512
#define TT 512
#define KRENORM 8
#define NBLK (BB / 2)   // 256 blocks, 2 chains (batches) per block

// ---------------------------------------------------------------------------
// Kernel 0: column max of transitions and E[i][j] = exp(T[i][j]-maxT[j])
// ---------------------------------------------------------------------------
__global__ __launch_bounds__(128) void crf_prep(const float* __restrict__ trans,
                                                float* __restrict__ E,
                                                float* __restrict__ maxT) {
    int j = threadIdx.x;
    if (j < CC) {
        float m = -INFINITY;
        for (int i = 0; i < CC; ++i) m = fmaxf(m, trans[i * CC + j]);
        maxT[j] = m;
        for (int i = 0; i < CC; ++i) E[i * CC + j] = __expf(trans[i * CC + j] - m);
    }
}

// ---------------------------------------------------------------------------
// Kernel 1: forward recurrence in LINEAR probability space, TWO independent
// batch-chains per block (shared Ecol registers, shared barriers — the second
// chain hides under the first chain's latency).
// Round-2/3 lesson: VGPR_Count=104 proved the compiler rematerializes the
// E-column global loads inside the loop; the empty "+v" asm makes each Ecol
// value opaque so it MUST stay in a register (expect VGPR >= ~170).
// Renorm every KRENORM steps costs no extra barrier: all threads re-read the
// previous p from LDS (broadcast) and compute the identical sum.
// ---------------------------------------------------------------------------
__global__ __launch_bounds__(128, 1) void crf_forward(const float* __restrict__ emissions,
                                                      const int* __restrict__ mask,
                                                      const float* __restrict__ start_t,
                                                      const float* __restrict__ end_t,
                                                      const float* __restrict__ E,
                                                      const float* __restrict__ maxT,
                                                      float* __restrict__ log_den) {
    const int bA = blockIdx.x;
    const int bB = blockIdx.x + NBLK;
    const int j  = threadIdx.x;          // 0..127, active j < 96
    const bool act = (j < CC);
    const int jc = act ? j : 0;          // clamped: loads always valid, no divergence

    __shared__ __align__(16) float pA[2][CC];
    __shared__ __align__(16) float pB[2][CC];
    __shared__ float red[4];

    // E column jc -> 96 VGPRs, then pin with opaque asm (no remat possible).
    float Ecol[CC];
#pragma unroll
    for (int i = 0; i < CC; ++i) Ecol[i] = E[i * CC + jc];
#pragma unroll
    for (int i = 0; i < CC; ++i) asm volatile("" : "+v"(Ecol[i]));

    const size_t baseA = (size_t)bA * TT * CC;
    const size_t baseB = (size_t)bB * TT * CC;
    const float mT   = maxT[jc];
    const float endv = end_t[jc];
    const float stv  = start_t[jc];

    // --- init: p = exp(lp0 - max(lp0)); S = max ---
    float lpA = act ? (stv + emissions[baseA + jc]) : -INFINITY;
    float lpB = act ? (stv + emissions[baseB + jc]) : -INFINITY;
    float mA = lpA, mB = lpB;
#pragma unroll
    for (int off = 32; off; off >>= 1) {
        mA = fmaxf(mA, __shfl_xor(mA, off));
        mB = fmaxf(mB, __shfl_xor(mB, off));
    }
    if ((j & 63) == 0) { red[j >> 6] = mA; red[2 + (j >> 6)] = mB; }
    __syncthreads();
    const float M0A = fmaxf(red[0], red[1]);
    const float M0B = fmaxf(red[2], red[3]);
    float pjA = act ? __expf(lpA - M0A) : 0.f;
    float pjB = act ? __expf(lpB - M0B) : 0.f;
    double SA = (double)M0A;
    double SB = (double)M0B;

    // prefetch t=1
    float emA = emissions[baseA + CC + jc];
    float emB = emissions[baseB + CC + jc];
    int   mkA = mask[bA * TT + 1];
    int   mkB = mask[bB * TT + 1];

    for (int t = 1; t < TT; ++t) {
        const float emAc = emA, emBc = emB;
        const int   mkAc = mkA, mkBc = mkB;
        const int   tn = (t + 1 < TT) ? t + 1 : t;
        emA = emissions[baseA + (size_t)tn * CC + jc];
        emB = emissions[baseB + (size_t)tn * CC + jc];
        mkA = mask[bA * TT + tn];
        mkB = mask[bB * TT + tn];

        float* bufA = pA[t & 1];
        float* bufB = pB[t & 1];
        if (act) { bufA[j] = pjA; bufB[j] = pjB; }
        const float scA = __expf(mT + emAc);   // off the matvec chain
        const float scB = __expf(mT + emBc);
        __syncthreads();   // single barrier per step (double-buffered p)

        // dual matvec, interleaved for issue-slot packing
        float a0 = 0.f, a1 = 0.f, a2 = 0.f, a3 = 0.f;
        float c0 = 0.f, c1 = 0.f, c2 = 0.f, c3 = 0.f;
#pragma unroll
        for (int i = 0; i < CC; i += 4) {
            const float4 va = *(const float4*)&bufA[i];
            const float4 vb = *(const float4*)&bufB[i];
            a0 = fmaf(va.x, Ecol[i + 0], a0);
            a1 = fmaf(va.y, Ecol[i + 1], a1);
            a2 = fmaf(va.z, Ecol[i + 2], a2);
            a3 = fmaf(va.w, Ecol[i + 3], a3);
            c0 = fmaf(vb.x, Ecol[i + 0], c0);
            c1 = fmaf(vb.y, Ecol[i + 1], c1);
            c2 = fmaf(vb.z, Ecol[i + 2], c2);
            c3 = fmaf(vb.w, Ecol[i + 3], c3);
        }
        const float qA = (a0 + a1) + (a2 + a3);
        const float qB = (c0 + c1) + (c2 + c3);

        if (act && mkAc) pjA = qA * scA;
        if (act && mkBc) pjB = qB * scB;

        if ((t & (KRENORM - 1)) == 0) {
            // renorm with sum of PREVIOUS p (still in LDS): identical,
            // deterministic value in every thread — no reduction, no barrier.
            float sA0 = 0.f, sA1 = 0.f, sB0 = 0.f, sB1 = 0.f;
#pragma unroll
            for (int i = 0; i < CC; i += 8) {
                const float4 xa0 = *(const float4*)&bufA[i];
                const float4 xa1 = *(const float4*)&bufA[i + 4];
                const float4 xb0 = *(const float4*)&bufB[i];
                const float4 xb1 = *(const float4*)&bufB[i + 4];
                sA0 += (xa0.x + xa0.y) + (xa0.z + xa0.w);
                sA1 += (xa1.x + xa1.y) + (xa1.z + xa1.w);
                sB0 += (xb0.x + xb0.y) + (xb0.z + xb0.w);
                sB1 += (xb1.x + xb1.y) + (xb1.z + xb1.w);
            }
            const float totA = sA0 + sA1;
            const float totB = sB0 + sB1;
            pjA *= (1.0f / totA);
            pjB *= (1.0f / totB);
            SA += (double)__logf(totA);
            SB += (double)__logf(totB);
        }
    }

    // --- final: log_den = S + log(sum_j p[j] * exp(end[j])) ---
    // pA[0]/pB[0] were last READ before the t=511 barrier -> safe to overwrite.
    const float eend = __expf(endv);
    if (act) { pA[0][j] = pjA * eend; pB[0][j] = pjB * eend; }
    __syncthreads();
    if (j < 2) {
        const float* buf = (j == 0) ? pA[0] : pB[0];
        float s0 = 0.f, s1 = 0.f;
#pragma unroll
        for (int i = 0; i < CC; i += 8) {
            const float4 x0 = *(const float4*)&buf[i];
            const float4 x1 = *(const float4*)&buf[i + 4];
            s0 += (x0.x + x0.y) + (x0.z + x0.w);
            s1 += (x1.x + x1.y) + (x1.z + x1.w);
        }
        const double S = (j == 0) ? SA : SB;
        const int    bb = (j == 0) ? bA : bB;
        log_den[bb] = (float)(S + (double)__logf(s0 + s1));
    }
}

// ---------------------------------------------------------------------------
// Kernel 2: joint likelihood (numerator) — one block per batch.
// ---------------------------------------------------------------------------
__global__ __launch_bounds__(256) void crf_joint(const float* __restrict__ emissions,
                                                 const int* __restrict__ tags,
                                                 const int* __restrict__ mask,
                                                 const float* __restrict__ trans,
                                                 const float* __restrict__ start_t,
                                                 const float* __restrict__ end_t,
                                                 float* __restrict__ log_num) {
    const int b = blockIdx.x;
    const int tid = threadIdx.x;
    float s = 0.f;
    int mcount = 0;
    for (int t = tid; t < TT; t += 256) {
        int tg = tags[b * TT + t];
        float em = emissions[((size_t)b * TT + t) * CC + tg];
        int mk = mask[b * TT + t];
        mcount += mk;
        if (t == 0) {
            s += start_t[tg] + em;  // t=0 term unmasked in reference
        } else {
            int tp = tags[b * TT + t - 1];
            s += mk ? (trans[tp * CC + tg] + em) : 0.f;
        }
    }
    __shared__ float sred[4];
    __shared__ int mred[4];
#pragma unroll
    for (int off = 32; off; off >>= 1) {
        s += __shfl_xor(s, off);
        mcount += __shfl_xor(mcount, off);
    }
    if ((tid & 63) == 0) { sred[tid >> 6] = s; mred[tid >> 6] = mcount; }
    __syncthreads();
    if (tid == 0) {
        float tot = (sred[0] + sred[1]) + (sred[2] + sred[3]);
        int mt = (mred[0] + mred[1]) + (mred[2] + mred[3]);
        int last_tag = tags[b * TT + (mt - 1)];
        log_num[b] = tot + end_t[last_tag];
    }
}

// ---------------------------------------------------------------------------
// Kernel 3: final mean(log_den - log_num)
// ---------------------------------------------------------------------------
__global__ __launch_bounds__(512) void crf_final(const float* __restrict__ log_den,
                                                 const float* __restrict__ log_num,
                                                 float* __restrict__ out) {
    const int tid = threadIdx.x;
    float d = log_den[tid] - log_num[tid];
#pragma unroll
    for (int off = 32; off; off >>= 1) d += __shfl_xor(d, off);
    __shared__ float sred[8];
    if ((tid & 63) == 0) sred[tid >> 6] = d;
    __syncthreads();
    if (tid == 0) {
        float tot = 0.f;
        for (int w = 0; w < 8; ++w) tot += sred[w];
        out[0] = tot / (float)BB;
    }
}

extern "C" void kernel_launch(void* const* d_in, const int* in_sizes, int n_in,
                              void* d_out, int out_size, void* d_ws, size_t ws_size,
                              hipStream_t stream) {
    const float* emissions = (const float*)d_in[0];
    const int*   tags      = (const int*)d_in[1];
    const int*   mask      = (const int*)d_in[2];
    const float* trans     = (const float*)d_in[3];
    const float* start_t   = (const float*)d_in[4];
    const float* end_t     = (const float*)d_in[5];
    float* out = (float*)d_out;

    float* ws      = (float*)d_ws;
    float* E       = ws;             // 9216 floats
    float* maxT    = ws + 9216;      // 96
    float* log_den = ws + 9312;      // 512
    float* log_num = ws + 9824;      // 512

    crf_prep<<<1, 128, 0, stream>>>(trans, E, maxT);
    crf_forward<<<NBLK, 128, 0, stream>>>(emissions, mask, start_t, end_t, E, maxT, log_den);
    crf_joint<<<BB, 256, 0, stream>>>(emissions, tags, mask, trans, start_t, end_t, log_num);
    crf_final<<<1, 512, 0, stream>>>(log_den, log_num, out);
}

// Round 5
// 401.324 us; speedup vs baseline: 1.3167x; 1.3167x over previous
//
#include <hip/hip_runtime.h>
#include <math.h>

#define CC 96
#define BB 512
#define TT 512

// ---------------------------------------------------------------------------
// Kernel 0: column max of transitions and E[i][j] = exp(T[i][j]-maxT[j])
// ---------------------------------------------------------------------------
__global__ __launch_bounds__(128) void crf_prep(const float* __restrict__ trans,
                                                float* __restrict__ E,
                                                float* __restrict__ maxT) {
    int j = threadIdx.x;
    if (j < CC) {
        float m = -INFINITY;
        for (int i = 0; i < CC; ++i) m = fmaxf(m, trans[i * CC + j]);
        maxT[j] = m;
        for (int i = 0; i < CC; ++i) E[i * CC + j] = __expf(trans[i * CC + j] - m);
    }
}

// ---------------------------------------------------------------------------
// Kernel 1: forward recurrence, linear probability space, one batch per block.
// Round-4 lesson: __syncthreads() lowers to s_waitcnt vmcnt(0)+s_barrier —
// it drained the emissions prefetch (HBM latency ~900cy) on EVERY step.
// Here the hot-loop barrier is raw s_barrier preceded by lgkmcnt(0) only
// (LDS visibility), so prefetch loads stay in flight across barriers and the
// compiler waits on them (counted vmcnt) only at the consume site ~2 steps
// later (unroll-2 + parity prefetch slots, no register copies).
// Ecol stays pinned in VGPRs via opaque asm (round-3 lesson, VGPR 104->156).
// Renorm every 8 steps reads the step's LDS p-buffer (deterministic,
// identical in all threads — no reduction, no extra barrier).
// ---------------------------------------------------------------------------
__global__ __launch_bounds__(128, 1) void crf_forward(const float* __restrict__ emissions,
                                                      const int* __restrict__ mask,
                                                      const float* __restrict__ start_t,
                                                      const float* __restrict__ end_t,
                                                      const float* __restrict__ E,
                                                      const float* __restrict__ maxT,
                                                      float* __restrict__ log_den) {
    const int b = blockIdx.x;
    const int j = threadIdx.x;          // 0..127, active j < 96
    const bool act = (j < CC);
    const int jc = act ? j : 0;         // clamped: loads always valid

    __shared__ __align__(16) float pbuf[2][CC];
    __shared__ float red[2];

    // E column jc -> 96 VGPRs, pinned with opaque asm (no remat possible).
    float Ecol[CC];
#pragma unroll
    for (int i = 0; i < CC; ++i) Ecol[i] = E[i * CC + jc];
#pragma unroll
    for (int i = 0; i < CC; ++i) asm volatile("" : "+v"(Ecol[i]));

    const size_t bbase = (size_t)b * TT * CC;
    const float mT   = maxT[jc];
    const float endv = end_t[jc];

    // --- init: p = exp(lp0 - max(lp0)); S = max ---
    float lp0 = act ? (start_t[jc] + emissions[bbase + jc]) : -INFINITY;
    float m0 = lp0;
#pragma unroll
    for (int off = 32; off; off >>= 1) m0 = fmaxf(m0, __shfl_xor(m0, off));
    if ((j & 63) == 0) red[j >> 6] = m0;
    __syncthreads();
    const float M0 = fmaxf(red[0], red[1]);
    float pj = act ? __expf(lp0 - M0) : 0.f;
    double S = (double)M0;

    // prefetch slots: slot1 = odd t, slot2 = even t
    float em1 = emissions[bbase + (size_t)1 * CC + jc];   // t=1
    int   mk1 = mask[b * TT + 1];
    float em2 = emissions[bbase + (size_t)2 * CC + jc];   // t=2
    int   mk2 = mask[b * TT + 2];

    // one forward step; caller passes this step's emission/mask and LDS parity
    auto STEP = [&](float emc, int mkc, int parity, bool do_renorm) {
        float* buf = pbuf[parity];
        if (act) buf[j] = pj;
        const float sc = __expf(mT + emc);          // off the matvec chain
        asm volatile("s_waitcnt lgkmcnt(0)" ::: "memory");
        __builtin_amdgcn_s_barrier();               // NO vmcnt drain

        float a0 = 0.f, a1 = 0.f, a2 = 0.f, a3 = 0.f;
        float a4 = 0.f, a5 = 0.f, a6 = 0.f, a7 = 0.f;
#pragma unroll
        for (int i = 0; i < CC; i += 8) {
            const float4 v0 = *(const float4*)&buf[i];
            const float4 v1 = *(const float4*)&buf[i + 4];
            a0 = fmaf(v0.x, Ecol[i + 0], a0);
            a1 = fmaf(v0.y, Ecol[i + 1], a1);
            a2 = fmaf(v0.z, Ecol[i + 2], a2);
            a3 = fmaf(v0.w, Ecol[i + 3], a3);
            a4 = fmaf(v1.x, Ecol[i + 4], a4);
            a5 = fmaf(v1.y, Ecol[i + 5], a5);
            a6 = fmaf(v1.z, Ecol[i + 6], a6);
            a7 = fmaf(v1.w, Ecol[i + 7], a7);
        }
        const float q = ((a0 + a1) + (a2 + a3)) + ((a4 + a5) + (a6 + a7));
        if (act && mkc) pj = q * sc;

        if (do_renorm) {
            // sum of previous p (this step's buf): identical, deterministic
            // in every thread — no reduction, no barrier.
            float s0 = 0.f, s1 = 0.f;
#pragma unroll
            for (int i = 0; i < CC; i += 8) {
                const float4 x0 = *(const float4*)&buf[i];
                const float4 x1 = *(const float4*)&buf[i + 4];
                s0 += (x0.x + x0.y) + (x0.z + x0.w);
                s1 += (x1.x + x1.y) + (x1.z + x1.w);
            }
            const float tot = s0 + s1;
            pj *= (1.0f / tot);
            S += (double)__logf(tot);
        }
    };

    // main loop: pairs (t, t+1) for t = 1,3,...,509; epilogue t = 511.
    for (int t = 1; t < TT - 1; t += 2) {
        // --- odd sub-step t: consume slot1 (loaded 2 iters ago) ---
        const float emc1 = em1;     // vmcnt wait lands here (~2-step window)
        const int   mkc1 = mk1;
        if (t + 2 < TT) {
            em1 = emissions[bbase + (size_t)(t + 2) * CC + jc];
            mk1 = mask[b * TT + t + 2];
        }
        STEP(emc1, mkc1, t & 1, false);             // odd t never renorms

        // --- even sub-step t+1: consume slot2 ---
        const float emc2 = em2;
        const int   mkc2 = mk2;
        if (t + 3 < TT) {
            em2 = emissions[bbase + (size_t)(t + 3) * CC + jc];
            mk2 = mask[b * TT + t + 3];
        }
        STEP(emc2, mkc2, (t + 1) & 1, ((t + 1) & 7) == 0);
    }
    STEP(em1, mk1, 1, false);                       // t = 511 (odd)

    // --- final: log_den = S + log(sum_j p[j] * exp(end[j])) ---
    // pbuf[0] was last consumed before the final barrier -> safe to overwrite.
    if (act) pbuf[0][j] = pj * __expf(endv);
    __syncthreads();
    if (j == 0) {
        float s0 = 0.f, s1 = 0.f;
#pragma unroll
        for (int i = 0; i < CC; i += 8) {
            const float4 x0 = *(const float4*)&pbuf[0][i];
            const float4 x1 = *(const float4*)&pbuf[0][i + 4];
            s0 += (x0.x + x0.y) + (x0.z + x0.w);
            s1 += (x1.x + x1.y) + (x1.z + x1.w);
        }
        log_den[b] = (float)(S + (double)__logf(s0 + s1));
    }
}

// ---------------------------------------------------------------------------
// Kernel 2: joint likelihood (numerator) — one block per batch.
// ---------------------------------------------------------------------------
__global__ __launch_bounds__(256) void crf_joint(const float* __restrict__ emissions,
                                                 const int* __restrict__ tags,
                                                 const int* __restrict__ mask,
                                                 const float* __restrict__ trans,
                                                 const float* __restrict__ start_t,
                                                 const float* __restrict__ end_t,
                                                 float* __restrict__ log_num) {
    const int b = blockIdx.x;
    const int tid = threadIdx.x;
    float s = 0.f;
    int mcount = 0;
    for (int t = tid; t < TT; t += 256) {
        int tg = tags[b * TT + t];
        float em = emissions[((size_t)b * TT + t) * CC + tg];
        int mk = mask[b * TT + t];
        mcount += mk;
        if (t == 0) {
            s += start_t[tg] + em;  // t=0 term unmasked in reference
        } else {
            int tp = tags[b * TT + t - 1];
            s += mk ? (trans[tp * CC + tg] + em) : 0.f;
        }
    }
    __shared__ float sred[4];
    __shared__ int mred[4];
#pragma unroll
    for (int off = 32; off; off >>= 1) {
        s += __shfl_xor(s, off);
        mcount += __shfl_xor(mcount, off);
    }
    if ((tid & 63) == 0) { sred[tid >> 6] = s; mred[tid >> 6] = mcount; }
    __syncthreads();
    if (tid == 0) {
        float tot = (sred[0] + sred[1]) + (sred[2] + sred[3]);
        int mt = (mred[0] + mred[1]) + (mred[2] + mred[3]);
        int last_tag = tags[b * TT + (mt - 1)];
        log_num[b] = tot + end_t[last_tag];
    }
}

// ---------------------------------------------------------------------------
// Kernel 3: final mean(log_den - log_num)
// ---------------------------------------------------------------------------
__global__ __launch_bounds__(512) void crf_final(const float* __restrict__ log_den,
                                                 const float* __restrict__ log_num,
                                                 float* __restrict__ out) {
    const int tid = threadIdx.x;
    float d = log_den[tid] - log_num[tid];
#pragma unroll
    for (int off = 32; off; off >>= 1) d += __shfl_xor(d, off);
    __shared__ float sred[8];
    if ((tid & 63) == 0) sred[tid >> 6] = d;
    __syncthreads();
    if (tid == 0) {
        float tot = 0.f;
        for (int w = 0; w < 8; ++w) tot += sred[w];
        out[0] = tot / (float)BB;
    }
}

extern "C" void kernel_launch(void* const* d_in, const int* in_sizes, int n_in,
                              void* d_out, int out_size, void* d_ws, size_t ws_size,
                              hipStream_t stream) {
    const float* emissions = (const float*)d_in[0];
    const int*   tags      = (const int*)d_in[1];
    const int*   mask      = (const int*)d_in[2];
    const float* trans     = (const float*)d_in[3];
    const float* start_t   = (const float*)d_in[4];
    const float* end_t     = (const float*)d_in[5];
    float* out = (float*)d_out;

    float* ws      = (float*)d_ws;
    float* E       = ws;             // 9216 floats
    float* maxT    = ws + 9216;      // 96
    float* log_den = ws + 9312;      // 512
    float* log_num = ws + 9824;      // 512

    crf_prep<<<1, 128, 0, stream>>>(trans, E, maxT);
    crf_forward<<<BB, 128, 0, stream>>>(emissions, mask, start_t, end_t, E, maxT, log_den);
    crf_joint<<<BB, 256, 0, stream>>>(emissions, tags, mask, trans, start_t, end_t, log_num);
    crf_final<<<1, 512, 0, stream>>>(log_den, log_num, out);
}